// Round 5
// baseline (830.286 us; speedup 1.0000x reference)
//
#include <hip/hip_runtime.h>

// RecursiveNN, perfect binary tree, 8192 leaves, EMBED=512 — fused mega-kernel.
// Closed-form post-order indexing: node at height h, position m:
//   idx = ((m+1)<<(h+1)) - 2 - popc(m);  left = idx - (1<<h);  right = idx - 1
// Numerics: fp16 hi+lo split H and W; 3-term MFMA (hh,hl,lh) => ~fp32 accuracy
// (measured absmax = fp32-reorder noise, 36x under threshold; op-order kept
// identical to the validated round-4 kernels).
// Single persistent kernel, 256 blocks (1/CU, co-resident), grid barriers via
// device-scope atomics (bounded spin: failure => wrong answer, not a hang).
// Phases: [pack W + leaves] -> h=1..4 (64x128 LDS-staged MFMA tiles) ->
//         h=5..13 (16x16 split-K tiles) -> projection.

#define EMBED 512
#define K2    1024
#define WOFF  (EMBED * K2)   // halves between Whp and Wlp (contiguous)
#define NBLK  256
#define LVL   13

typedef _Float16 half8 __attribute__((ext_vector_type(8)));
typedef float    floatx4 __attribute__((ext_vector_type(4)));

__device__ __forceinline__ float relu_f(float x) { return fmaxf(x, 0.0f); }

#define GLDS16(gp, lp)                                                        \
    __builtin_amdgcn_global_load_lds(                                         \
        (const __attribute__((address_space(1))) void*)(gp),                  \
        (__attribute__((address_space(3))) void*)(lp), 16, 0, 0)

// Grid barrier: one arrival atomic per block, device (agent) scope, acquire
// spin. Counter slots are single-use per launch (zeroed by hipMemsetAsync).
__device__ __forceinline__ void gsync(int* cnt, int idx)
{
    __syncthreads();
    if (threadIdx.x == 0) {
        __threadfence();   // release: make this block's writes device-visible
        __hip_atomic_fetch_add(&cnt[idx], 1, __ATOMIC_RELEASE,
                               __HIP_MEMORY_SCOPE_AGENT);
        int spins = 0;
        while (__hip_atomic_load(&cnt[idx], __ATOMIC_ACQUIRE,
                                 __HIP_MEMORY_SCOPE_AGENT) < NBLK) {
            __builtin_amdgcn_s_sleep(2);
            if (++spins > (1 << 22)) break;   // degrade, don't deadlock
        }
        __threadfence();   // acquire: discard stale cached lines
    }
    __syncthreads();
}

__global__ __launch_bounds__(256, 1)
void mega(const int* __restrict__ word, const float* __restrict__ emb,
          const float* __restrict__ W, const float* __restrict__ bW,
          const float* __restrict__ P, const float* __restrict__ bP,
          _Float16* Hh, _Float16* Hl,
          _Float16* Whp,                    // Wlp = Whp + WOFF
          int* cnt, float* out, int nNodes, int nLeaves, int hoff)
{
    __shared__ _Float16 lds[48 * 512];      // 48 KB; phases reuse it
    float* red = (float*)lds;               // split-K reduction view (4 KB)

    int tid = threadIdx.x;
    int wave = tid >> 6, lane = tid & 63;
    int q = lane >> 4, r = lane & 15;
    int wm = wave >> 1, wn = wave & 1;

    // ================= P0: pack W (hi/lo, B-fragment order) + leaves =======
    {
        // 65536 pack jobs == 256 blocks x 256 threads: one each.
        int t = blockIdx.x * 256 + tid;
        int n = t >> 7, kc = t & 127;            // kc: chunk of 8 k
        const float* src = W + (size_t)n * K2 + kc * 8;
        int s = kc >> 2, quad = kc & 3;
        int ln = (quad << 4) | (n & 15);
        size_t off = (size_t)(n >> 4) * 16384 + (size_t)s * 512 + (size_t)ln * 8;
        half8 hi, lo;
#pragma unroll
        for (int j = 0; j < 8; ++j) {
            float w = src[j];
            _Float16 h16 = (_Float16)w;
            hi[j] = h16;
            lo[j] = (_Float16)(w - (float)h16);
        }
        *(half8*)(Whp + off) = hi;
        *(half8*)(Whp + WOFF + off) = lo;
    }
    {
        // 8192 leaves == 256 blocks x 4 waves x 8 leaves.
#pragma unroll
        for (int i = 0; i < 8; ++i) {
            int m = blockIdx.x * 32 + wave * 8 + i;
            if (m < nLeaves) {
                int idx = 2 * m - __popc(m);
                int wd = word[idx];
                const float4* src = (const float4*)(emb + (size_t)wd * EMBED) + lane * 2;
                float4 a = src[0], b = src[1];
                float v[8] = {a.x, a.y, a.z, a.w, b.x, b.y, b.z, b.w};
                half8 hi, lo;
#pragma unroll
                for (int j = 0; j < 8; ++j) {
                    float x = relu_f(v[j]);
                    _Float16 h16 = (_Float16)x;
                    hi[j] = h16;
                    lo[j] = (_Float16)(x - (float)h16);
                }
                *(half8*)(Hh + (size_t)idx * EMBED + lane * 8) = hi;
                *(half8*)(Hl + (size_t)idx * EMBED + lane * 8) = lo;
            }
        }
    }
    gsync(cnt, 0);

    // ================= P1: levels h=1..4 — 64x128 LDS-staged tiles =========
    for (int h = 1; h <= 4; ++h) {
        int M = 1 << (LVL - h);
        int mtiles = M >> 6;
        int jobs = mtiles * 4;                   // h=1: 256, then 128/64/32
        if ((int)blockIdx.x < jobs) {
            int bx = blockIdx.x % mtiles, by = blockIdx.x / mtiles;
            int bm0 = bx * 64, bn0 = by * 128;

            int ms = bm0 + wave * 16 + r;
            if (ms >= M) ms = M - 1;
            int node_s = ((ms + 1) << (h + 1)) - 2 - __popc(ms);
            int aL = (node_s - (1 << h)) * EMBED + q * 8;
            int aR = (node_s - 1) * EMBED + q * 8;

            floatx4 acc[2][4];
#pragma unroll
            for (int i = 0; i < 2; ++i)
#pragma unroll
                for (int j = 0; j < 4; ++j) acc[i][j] = (floatx4){0.f, 0.f, 0.f, 0.f};

            for (int kc = 0; kc < 16; ++kc) {
                int abase = (kc < 8) ? (aL + kc * 64) : (aR + (kc - 8) * 64);
#pragma unroll
                for (int i = 0; i < 4; ++i) {    // i = s2*2 + hl
                    int s2 = i >> 1, hl = i & 1;
                    const _Float16* gp = Hh + abase + s2 * 32 + (hl ? hoff : 0);
                    GLDS16(gp, &lds[(wave * 4 + i) * 512]);
                }
#pragma unroll
                for (int j = 0; j < 8; ++j) {    // B slot sid = wave*8 + j
                    int u = wave * 2 + (j >> 2), s2 = (j >> 1) & 1, hl = j & 1;
                    const _Float16* gp = Whp + (size_t)(by * 8 + u) * 16384
                                       + (kc * 2 + s2) * 512 + (hl ? WOFF : 0) + lane * 8;
                    GLDS16(gp, &lds[8192 + (wave * 8 + j) * 512]);
                }
                __syncthreads();

#pragma unroll
                for (int s2 = 0; s2 < 2; ++s2) {
                    half8 ah[2], al[2], bh[4], bl[4];
#pragma unroll
                    for (int t2 = 0; t2 < 2; ++t2) {
                        int t = wm * 2 + t2;
                        ah[t2] = *(const half8*)&lds[((t * 2 + s2) * 2 + 0) * 512 + lane * 8];
                        al[t2] = *(const half8*)&lds[((t * 2 + s2) * 2 + 1) * 512 + lane * 8];
                    }
#pragma unroll
                    for (int u2 = 0; u2 < 4; ++u2) {
                        int u = wn * 4 + u2;
                        bh[u2] = *(const half8*)&lds[8192 + ((u * 2 + s2) * 2 + 0) * 512 + lane * 8];
                        bl[u2] = *(const half8*)&lds[8192 + ((u * 2 + s2) * 2 + 1) * 512 + lane * 8];
                    }
#pragma unroll
                    for (int t2 = 0; t2 < 2; ++t2)
#pragma unroll
                        for (int u2 = 0; u2 < 4; ++u2) {
                            acc[t2][u2] = __builtin_amdgcn_mfma_f32_16x16x32_f16(ah[t2], bh[u2], acc[t2][u2], 0, 0, 0);
                            acc[t2][u2] = __builtin_amdgcn_mfma_f32_16x16x32_f16(ah[t2], bl[u2], acc[t2][u2], 0, 0, 0);
                            acc[t2][u2] = __builtin_amdgcn_mfma_f32_16x16x32_f16(al[t2], bh[u2], acc[t2][u2], 0, 0, 0);
                        }
                }
                __syncthreads();
            }

#pragma unroll
            for (int t2 = 0; t2 < 2; ++t2)
#pragma unroll
                for (int reg = 0; reg < 4; ++reg) {
                    int m = bm0 + (wm * 2 + t2) * 16 + q * 4 + reg;
                    if (m < M) {
                        int node = ((m + 1) << (h + 1)) - 2 - __popc(m);
#pragma unroll
                        for (int u2 = 0; u2 < 4; ++u2) {
                            int col = bn0 + (wn * 4 + u2) * 16 + r;
                            float v = relu_f(acc[t2][u2][reg] + bW[col]);
                            _Float16 hi = (_Float16)v;
                            Hh[(size_t)node * EMBED + col] = hi;
                            Hl[(size_t)node * EMBED + col] = (_Float16)(v - (float)hi);
                        }
                    }
                }
        }
        gsync(cnt, h);
    }

    // ================= P2: levels h=5..13 — 16x16 split-K tiles ============
    for (int h = 5; h <= LVL; ++h) {
        int M = 1 << (LVL - h);
        int jm = (M + 15) >> 4;
        int jobs = jm * 32;
        for (int job = blockIdx.x; job < jobs; job += NBLK) {
            int mt = job % jm, u = job / jm;

            int m = mt * 16 + r;
            if (m >= M) m = M - 1;
            int idx = ((m + 1) << (h + 1)) - 2 - __popc(m);
            int childRow = (wave < 2) ? (idx - (1 << h)) : (idx - 1);
            int kbase = (wave & 1) * 256;
            const _Float16* pAh = Hh + (size_t)childRow * EMBED + kbase + q * 8;
            const _Float16* pAl = Hl + (size_t)childRow * EMBED + kbase + q * 8;
            const _Float16* pB  = Whp + (size_t)u * 16384 + (size_t)(wave * 8) * 512 + lane * 8;

            floatx4 acc = (floatx4){0.f, 0.f, 0.f, 0.f};
#pragma unroll
            for (int s = 0; s < 8; ++s) {
                half8 ah = *(const half8*)(pAh + s * 32);
                half8 al = *(const half8*)(pAl + s * 32);
                half8 bh = *(const half8*)(pB + s * 512);
                half8 bl = *(const half8*)(pB + s * 512 + WOFF);
                acc = __builtin_amdgcn_mfma_f32_16x16x32_f16(ah, bh, acc, 0, 0, 0);
                acc = __builtin_amdgcn_mfma_f32_16x16x32_f16(ah, bl, acc, 0, 0, 0);
                acc = __builtin_amdgcn_mfma_f32_16x16x32_f16(al, bh, acc, 0, 0, 0);
            }
#pragma unroll
            for (int reg = 0; reg < 4; ++reg)
                red[wave * 256 + (q * 4 + reg) * 16 + r] = acc[reg];
            __syncthreads();

            int row = tid >> 4, col = tid & 15;
            float v = red[row * 16 + col] + red[256 + row * 16 + col]
                    + red[512 + row * 16 + col] + red[768 + row * 16 + col];
            int mm = mt * 16 + row;
            if (mm < M) {
                int node = ((mm + 1) << (h + 1)) - 2 - __popc(mm);
                int colg = u * 16 + col;
                float x = relu_f(v + bW[colg]);
                _Float16 hi = (_Float16)x;
                Hh[(size_t)node * EMBED + colg] = hi;
                Hl[(size_t)node * EMBED + colg] = (_Float16)(x - (float)hi);
            }
            __syncthreads();            // red reused by next job
        }
        gsync(cnt, h);
    }

    // ================= P3: projection ======================================
#pragma unroll
    for (int i = 0; i < 16; ++i) {
        int node = blockIdx.x * 64 + wave * 16 + i;
        if (node < nNodes) {
            half8 hv = *(const half8*)(Hh + (size_t)node * EMBED + lane * 8);
            half8 lv = *(const half8*)(Hl + (size_t)node * EMBED + lane * 8);
            float hx[8];
#pragma unroll
            for (int j = 0; j < 8; ++j) hx[j] = (float)hv[j] + (float)lv[j];
            float s[5];
#pragma unroll
            for (int c = 0; c < 5; ++c) {
                const float* p = P + c * EMBED + lane * 8;
                float4 p0 = *(const float4*)p;
                float4 p1 = *(const float4*)(p + 4);
                s[c] = hx[0] * p0.x + hx[1] * p0.y + hx[2] * p0.z + hx[3] * p0.w
                     + hx[4] * p1.x + hx[5] * p1.y + hx[6] * p1.z + hx[7] * p1.w;
            }
#pragma unroll
            for (int o = 32; o > 0; o >>= 1)
#pragma unroll
                for (int c = 0; c < 5; ++c)
                    s[c] += __shfl_down(s[c], o, 64);
            if (lane == 0) {
#pragma unroll
                for (int c = 0; c < 5; ++c)
                    out[(size_t)node * 5 + c] = s[c] + bP[c];
            }
        }
    }
}

// ---------------------------------------------------------------------------
extern "C" void kernel_launch(void* const* d_in, const int* in_sizes, int n_in,
                              void* d_out, int out_size, void* d_ws, size_t ws_size,
                              hipStream_t stream)
{
    const int*   word = (const int*)d_in[1];
    const float* emb  = (const float*)d_in[4];
    const float* W    = (const float*)d_in[5];
    const float* bW   = (const float*)d_in[6];
    const float* P    = (const float*)d_in[7];
    const float* bP   = (const float*)d_in[8];
    float* out = (float*)d_out;

    int nNodes  = in_sizes[0];            // 16383
    int nLeaves = (nNodes + 1) / 2;       // 8192

    int hoff = (nNodes + 1) * EMBED;      // halves between Hh and Hl
    _Float16* Hh  = (_Float16*)d_ws;
    _Float16* Hl  = Hh + hoff;
    _Float16* Whp = Hl + hoff;            // hi; lo at +WOFF
    int* cnt = (int*)(Whp + 2 * WOFF);    // 14 barrier slots

    hipMemsetAsync(cnt, 0, 64, stream);
    mega<<<dim3(NBLK), dim3(256), 0, stream>>>(
        word, emb, W, bW, P, bP, Hh, Hl, Whp, cnt, out, nNodes, nLeaves, hoff);
}

// Round 6
// 409.648 us; speedup vs baseline: 2.0268x; 2.0268x over previous
//
#include <hip/hip_runtime.h>

// RecursiveNN, perfect binary tree, 8192 leaves, EMBED=512.
// idx(h,m) = ((m+1)<<(h+1)) - 2 - popc(m); left = idx - (1<<h); right = idx-1.
// fp16 hi+lo split H and W, 3-term MFMA (hh,hl,lh) => fp32-level accuracy.
// Structure (7 dispatches):
//   packleaf -> gemm_big h=1..4 (BK=128 LDS-staged, 64x128 tiles)
//   -> tail h=5..13 in ONE kernel: each physical XCD redundantly computes all
//      tail levels (work-claim + done-count atomics per XCD; same-XCD L2 is
//      coherent for plain stores, so NO fences -> avoids round-5's ~50us/barrier
//      L2-writeback storms) -> projection.

#define EMBED 512
#define K2    1024
#define WOFF  (EMBED * K2)

typedef _Float16 half8 __attribute__((ext_vector_type(8)));
typedef float    floatx4 __attribute__((ext_vector_type(4)));

__device__ __forceinline__ float relu_f(float x) { return fmaxf(x, 0.0f); }

#define GLDS16(gp, lp)                                                        \
    __builtin_amdgcn_global_load_lds(                                         \
        (const __attribute__((address_space(1))) void*)(gp),                  \
        (__attribute__((address_space(3))) void*)(lp), 16, 0, 0)

// ---------------------------------------------------------------------------
// pack W into fp16 hi/lo MFMA-B fragment order + leaves + zero tail counters.
__global__ __launch_bounds__(256)
void packleaf(const float* __restrict__ W, const float* __restrict__ emb,
              const int* __restrict__ word,
              _Float16* __restrict__ Whp,       // lo at +WOFF
              _Float16* __restrict__ Hh, _Float16* __restrict__ Hl,
              int* __restrict__ cnt, int nLeaves)
{
    int tid = threadIdx.x;
    int wave = tid >> 6, lane = tid & 63;

    if (blockIdx.x == 0) cnt[tid] = 0;          // 256 ints: claim/done slots

    {   // ---- pack: 65536 jobs = 256 blocks x 256 threads
        int t = blockIdx.x * 256 + tid;
        int n = t >> 7, kc = t & 127;
        const float* src = W + (size_t)n * K2 + kc * 8;
        int s = kc >> 2, quad = kc & 3;
        int ln = (quad << 4) | (n & 15);
        size_t off = (size_t)(n >> 4) * 16384 + (size_t)s * 512 + (size_t)ln * 8;
        half8 hi, lo;
#pragma unroll
        for (int j = 0; j < 8; ++j) {
            float w = src[j];
            _Float16 h16 = (_Float16)w;
            hi[j] = h16;
            lo[j] = (_Float16)(w - (float)h16);
        }
        *(half8*)(Whp + off) = hi;
        *(half8*)(Whp + WOFF + off) = lo;
    }
    {   // ---- leaves: 8192 = 256 blocks x 4 waves x 8
#pragma unroll
        for (int i = 0; i < 8; ++i) {
            int m = blockIdx.x * 32 + wave * 8 + i;
            if (m < nLeaves) {
                int idx = 2 * m - __popc(m);
                int wd = word[idx];
                const float4* src = (const float4*)(emb + (size_t)wd * EMBED) + lane * 2;
                float4 a = src[0], b = src[1];
                float v[8] = {a.x, a.y, a.z, a.w, b.x, b.y, b.z, b.w};
                half8 hi, lo;
#pragma unroll
                for (int j = 0; j < 8; ++j) {
                    float x = relu_f(v[j]);
                    _Float16 h16 = (_Float16)x;
                    hi[j] = h16;
                    lo[j] = (_Float16)(x - (float)h16);
                }
                *(half8*)(Hh + (size_t)idx * EMBED + lane * 8) = hi;
                *(half8*)(Hl + (size_t)idx * EMBED + lane * 8) = lo;
            }
        }
    }
}

// ---------------------------------------------------------------------------
// Big-level GEMM (h=1..4). Block 64 rows x 128 cols, 4 waves 2x2.
// BK=128: 8 K-chunks (halves the serial K-latency rounds vs BK=64 at
// 1 block/CU). Per chunk LDS = A 32KB + B 64KB = 96KB, staged via
// global_load_lds w=16 in exact fragment order.
__global__ __launch_bounds__(256, 1)
void gemm_big(const _Float16* H,                // Hh; Hl = H + hoff
              const _Float16* __restrict__ Wp,  // Whp; Wlp = Wp + WOFF
              const float* __restrict__ bW,
              _Float16* Hh, _Float16* Hl,
              int h, int M, int hoff)
{
    __shared__ _Float16 lds[49152];             // 96 KB: A[0,16384) B[16384,49152)

    int tid = threadIdx.x;
    int wave = tid >> 6, lane = tid & 63;
    int q = lane >> 4, r = lane & 15;
    int wm = wave >> 1, wn = wave & 1;
    int bm0 = blockIdx.x * 64, bn0 = blockIdx.y * 128;

    int ms = bm0 + wave * 16 + r;
    if (ms >= M) ms = M - 1;
    int node_s = ((ms + 1) << (h + 1)) - 2 - __popc(ms);
    int aL = (node_s - (1 << h)) * EMBED + q * 8;
    int aR = (node_s - 1) * EMBED + q * 8;

    floatx4 acc[2][4];
#pragma unroll
    for (int i = 0; i < 2; ++i)
#pragma unroll
        for (int j = 0; j < 4; ++j) acc[i][j] = (floatx4){0.f, 0.f, 0.f, 0.f};

    for (int kc = 0; kc < 8; ++kc) {            // BK=128
        int abase = ((kc < 4) ? aL : aR) + (kc & 3) * 128;
#pragma unroll
        for (int i = 0; i < 8; ++i) {           // A: i = s2*2 + hl, s2 in [0,4)
            int s2 = i >> 1, hl = i & 1;
            const _Float16* gp = H + abase + s2 * 32 + (hl ? hoff : 0);
            GLDS16(gp, &lds[(wave * 8 + i) * 512]);
        }
#pragma unroll
        for (int j = 0; j < 16; ++j) {          // B slot id = wave*16 + j
            int u = wave * 2 + (j >> 3), s2 = (j >> 1) & 3, hl = j & 1;
            const _Float16* gp = Wp + (size_t)(blockIdx.y * 8 + u) * 16384
                               + (kc * 4 + s2) * 512 + (hl ? WOFF : 0) + lane * 8;
            GLDS16(gp, &lds[16384 + (wave * 16 + j) * 512]);
        }
        __syncthreads();

#pragma unroll
        for (int s2 = 0; s2 < 4; ++s2) {
            half8 ah[2], al[2], bh[4], bl[4];
#pragma unroll
            for (int t2 = 0; t2 < 2; ++t2) {
                int t = wm * 2 + t2;
                ah[t2] = *(const half8*)&lds[(t * 8 + s2 * 2 + 0) * 512 + lane * 8];
                al[t2] = *(const half8*)&lds[(t * 8 + s2 * 2 + 1) * 512 + lane * 8];
            }
#pragma unroll
            for (int u2 = 0; u2 < 4; ++u2) {
                int u = wn * 4 + u2;
                bh[u2] = *(const half8*)&lds[16384 + (u * 8 + s2 * 2 + 0) * 512 + lane * 8];
                bl[u2] = *(const half8*)&lds[16384 + (u * 8 + s2 * 2 + 1) * 512 + lane * 8];
            }
#pragma unroll
            for (int t2 = 0; t2 < 2; ++t2)
#pragma unroll
                for (int u2 = 0; u2 < 4; ++u2) {
                    acc[t2][u2] = __builtin_amdgcn_mfma_f32_16x16x32_f16(ah[t2], bh[u2], acc[t2][u2], 0, 0, 0);
                    acc[t2][u2] = __builtin_amdgcn_mfma_f32_16x16x32_f16(ah[t2], bl[u2], acc[t2][u2], 0, 0, 0);
                    acc[t2][u2] = __builtin_amdgcn_mfma_f32_16x16x32_f16(al[t2], bh[u2], acc[t2][u2], 0, 0, 0);
                }
        }
        __syncthreads();
    }

#pragma unroll
    for (int t2 = 0; t2 < 2; ++t2)
#pragma unroll
        for (int reg = 0; reg < 4; ++reg) {
            int m = bm0 + (wm * 2 + t2) * 16 + q * 4 + reg;
            if (m < M) {
                int node = ((m + 1) << (h + 1)) - 2 - __popc(m);
#pragma unroll
                for (int u2 = 0; u2 < 4; ++u2) {
                    int col = bn0 + (wn * 4 + u2) * 16 + r;
                    float v = relu_f(acc[t2][u2][reg] + bW[col]);
                    _Float16 hi = (_Float16)v;
                    Hh[(size_t)node * EMBED + col] = hi;
                    Hl[(size_t)node * EMBED + col] = (_Float16)(v - (float)hi);
                }
            }
        }
}

// ---------------------------------------------------------------------------
// Tail: levels h=5..13, one launch. Each physical XCD computes ALL tail jobs
// redundantly (identical values -> cross-XCD cache copies benign; consumers
// only ever read their own XCD's L2-visible data -> no fences). Level gating:
// per-XCD claim/done atomic counters (globally coherent RMWs). Deadlock-free:
// a lone block self-serves every job. Job = 16 rows x 64 cols, full K=1024;
// 4 waves, wave w owns n-tile c*4+w, direct-global fragments.
__global__ __launch_bounds__(256)
void tail(_Float16* Hh, _Float16* Hl,
          const _Float16* __restrict__ Wp,      // Whp; Wlp = Wp + WOFF
          const float* __restrict__ bW,
          int* __restrict__ cnt)
{
    __shared__ int sjob;
    int tid = threadIdx.x;
    int wave = tid >> 6, lane = tid & 63;
    int q = lane >> 4, r = lane & 15;

    int g = (int)__builtin_amdgcn_s_getreg((31 << 11) | 20) & 7;  // HW_REG_XCC_ID

    for (int h = 5; h <= 13; ++h) {
        int lM = 13 - h;
        int M = 1 << lM;
        int lmt = (lM > 4) ? (lM - 4) : 0;      // log2(#row-stripes)
        int jobs = (1 << lmt) * 8;              // 8 col-chunks of 64
        int* pc = &cnt[g * 32 + (h - 5)];
        int* pd = &cnt[g * 32 + 16 + (h - 5)];

        for (;;) {
            if (tid == 0) sjob = atomicAdd(pc, 1);
            __syncthreads();
            int job = sjob;
            if (job >= jobs) { __syncthreads(); break; }

            int s = job & ((1 << lmt) - 1);     // row stripe
            int c = job >> lmt;                 // col chunk (64 cols)
            int m = s * 16 + r;
            if (m >= M) m = M - 1;
            int idx = ((m + 1) << (h + 1)) - 2 - __popc(m);
            const _Float16* pLh = Hh + (size_t)(idx - (1 << h)) * EMBED + q * 8;
            const _Float16* pLl = Hl + (size_t)(idx - (1 << h)) * EMBED + q * 8;
            const _Float16* pRh = Hh + (size_t)(idx - 1) * EMBED + q * 8;
            const _Float16* pRl = Hl + (size_t)(idx - 1) * EMBED + q * 8;
            const _Float16* pB  = Wp + (size_t)(c * 4 + wave) * 16384 + lane * 8;

            floatx4 acc = (floatx4){0.f, 0.f, 0.f, 0.f};
#pragma unroll 8
            for (int k = 0; k < 32; ++k) {
                half8 ah = *(const half8*)((k < 16) ? (pLh + k * 32) : (pRh + (k - 16) * 32));
                half8 al = *(const half8*)((k < 16) ? (pLl + k * 32) : (pRl + (k - 16) * 32));
                half8 bh = *(const half8*)(pB + k * 512);
                half8 bl = *(const half8*)(pB + k * 512 + WOFF);
                acc = __builtin_amdgcn_mfma_f32_16x16x32_f16(ah, bh, acc, 0, 0, 0);
                acc = __builtin_amdgcn_mfma_f32_16x16x32_f16(ah, bl, acc, 0, 0, 0);
                acc = __builtin_amdgcn_mfma_f32_16x16x32_f16(al, bh, acc, 0, 0, 0);
            }
            int colg = (c * 4 + wave) * 16 + r;
            float bw = bW[colg];
#pragma unroll
            for (int reg = 0; reg < 4; ++reg) {
                int mm = s * 16 + q * 4 + reg;
                if (mm < M) {
                    int node = ((mm + 1) << (h + 1)) - 2 - __popc(mm);
                    float v = relu_f(acc[reg] + bw);
                    _Float16 hi = (_Float16)v;
                    Hh[(size_t)node * EMBED + colg] = hi;
                    Hl[(size_t)node * EMBED + colg] = (_Float16)(v - (float)hi);
                }
            }
            __syncthreads();                    // drains stores (vmcnt 0)
            if (tid == 0) atomicAdd(pd, 1);
        }

        if (tid == 0) {                         // wait level complete (this XCD)
            int spins = 0;
            while (atomicAdd(pd, 0) < jobs) {
                __builtin_amdgcn_s_sleep(2);
                if (++spins > (1 << 24)) break; // degrade, never hang
            }
        }
        __syncthreads();
    }
}

// ---------------------------------------------------------------------------
__global__ __launch_bounds__(256)
void out_kernel(const _Float16* __restrict__ Hh, const _Float16* __restrict__ Hl,
                const float* __restrict__ P, const float* __restrict__ bP,
                float* __restrict__ out, int nNodes)
{
    int t = blockIdx.x * 256 + threadIdx.x;
    int node = t >> 6, lane = t & 63;
    if (node >= nNodes) return;
    half8 hv = *(const half8*)(Hh + (size_t)node * EMBED + lane * 8);
    half8 lv = *(const half8*)(Hl + (size_t)node * EMBED + lane * 8);
    float hx[8];
#pragma unroll
    for (int j = 0; j < 8; ++j) hx[j] = (float)hv[j] + (float)lv[j];
    float s[5];
#pragma unroll
    for (int c = 0; c < 5; ++c) {
        const float* p = P + c * EMBED + lane * 8;
        float4 p0 = *(const float4*)p;
        float4 p1 = *(const float4*)(p + 4);
        s[c] = hx[0] * p0.x + hx[1] * p0.y + hx[2] * p0.z + hx[3] * p0.w
             + hx[4] * p1.x + hx[5] * p1.y + hx[6] * p1.z + hx[7] * p1.w;
    }
#pragma unroll
    for (int o = 32; o > 0; o >>= 1)
#pragma unroll
        for (int c = 0; c < 5; ++c)
            s[c] += __shfl_down(s[c], o, 64);
    if (lane == 0) {
#pragma unroll
        for (int c = 0; c < 5; ++c)
            out[(size_t)node * 5 + c] = s[c] + bP[c];
    }
}

// ---------------------------------------------------------------------------
extern "C" void kernel_launch(void* const* d_in, const int* in_sizes, int n_in,
                              void* d_out, int out_size, void* d_ws, size_t ws_size,
                              hipStream_t stream)
{
    const int*   word = (const int*)d_in[1];
    const float* emb  = (const float*)d_in[4];
    const float* W    = (const float*)d_in[5];
    const float* bW   = (const float*)d_in[6];
    const float* P    = (const float*)d_in[7];
    const float* bP   = (const float*)d_in[8];
    float* out = (float*)d_out;

    int nNodes  = in_sizes[0];            // 16383
    int nLeaves = (nNodes + 1) / 2;       // 8192

    int hoff = (nNodes + 1) * EMBED;      // halves between Hh and Hl
    _Float16* Hh  = (_Float16*)d_ws;
    _Float16* Hl  = Hh + hoff;
    _Float16* Whp = Hl + hoff;            // hi; lo at +WOFF
    int* cnt = (int*)(Whp + 2 * WOFF);    // 256 ints: per-XCD claim/done

    packleaf<<<dim3(256), dim3(256), 0, stream>>>(
        W, emb, word, Whp, Hh, Hl, cnt, nLeaves);
    for (int h = 1; h <= 4; ++h) {
        int M = 1 << (13 - h);
        gemm_big<<<dim3(M / 64, 4), dim3(256), 0, stream>>>(
            Hh, Whp, bW, Hh, Hl, h, M, hoff);
    }
    tail<<<dim3(256), dim3(256), 0, stream>>>(Hh, Hl, Whp, bW, cnt);
    out_kernel<<<dim3((nNodes * 64 + 255) / 256), dim3(256), 0, stream>>>(
        Hh, Hl, P, bP, out, nNodes);
}

// Round 8
// 273.395 us; speedup vs baseline: 3.0369x; 1.4984x over previous
//
#include <hip/hip_runtime.h>

// RecursiveNN, perfect binary tree, 8192 leaves, EMBED=512.
// idx(h,m) = ((m+1)<<(h+1)) - 2 - popc(m); left = idx - (1<<h); right = idx-1.
// fp16 hi+lo split H and W, 3-term MFMA (hh,hl,lh) => fp32-level accuracy.
// ALL sync via kernel boundaries (rounds 5-7 showed intra-kernel grid sync on
// MI355X is a tarpit: agent-fence L2-writeback storms ~50us/barrier, RMW-spin
// serialization ~20us/level, and a replay-time crash). 15 dispatches:
//   packleaf -> gemm_big h=1..4 (BK=128, 96KB LDS, 64x128 tiles)
//   -> gemm_splitk h=5..13 (16x16 tile, 4-way split-K) -> out_kernel.

#define EMBED 512
#define K2    1024
#define WOFF  (EMBED * K2)

typedef _Float16 half8 __attribute__((ext_vector_type(8)));
typedef float    floatx4 __attribute__((ext_vector_type(4)));

__device__ __forceinline__ float relu_f(float x) { return fmaxf(x, 0.0f); }

#define GLDS16(gp, lp)                                                        \
    __builtin_amdgcn_global_load_lds(                                         \
        (const __attribute__((address_space(1))) void*)(gp),                  \
        (__attribute__((address_space(3))) void*)(lp), 16, 0, 0)

// ---------------------------------------------------------------------------
// pack W into fp16 hi/lo MFMA-B fragment order + leaf embedding gather.
__global__ __launch_bounds__(256)
void packleaf(const float* __restrict__ W, const float* __restrict__ emb,
              const int* __restrict__ word,
              _Float16* __restrict__ Whp,       // lo at +WOFF
              _Float16* __restrict__ Hh, _Float16* __restrict__ Hl,
              int nLeaves)
{
    int tid = threadIdx.x;
    int wave = tid >> 6, lane = tid & 63;

    {   // ---- pack W: 65536 jobs = 256 blocks x 256 threads
        int t = blockIdx.x * 256 + tid;
        int n = t >> 7, kc = t & 127;
        const float* src = W + (size_t)n * K2 + kc * 8;
        int s = kc >> 2, quad = kc & 3;
        int ln = (quad << 4) | (n & 15);
        size_t off = (size_t)(n >> 4) * 16384 + (size_t)s * 512 + (size_t)ln * 8;
        half8 hi, lo;
#pragma unroll
        for (int j = 0; j < 8; ++j) {
            float w = src[j];
            _Float16 h16 = (_Float16)w;
            hi[j] = h16;
            lo[j] = (_Float16)(w - (float)h16);
        }
        *(half8*)(Whp + off) = hi;
        *(half8*)(Whp + WOFF + off) = lo;
    }
    {   // ---- leaves: 8192 = 256 blocks x 4 waves x 8
#pragma unroll
        for (int i = 0; i < 8; ++i) {
            int m = blockIdx.x * 32 + wave * 8 + i;
            if (m < nLeaves) {
                int idx = 2 * m - __popc(m);
                int wd = word[idx];
                const float4* src = (const float4*)(emb + (size_t)wd * EMBED) + lane * 2;
                float4 a = src[0], b = src[1];
                float v[8] = {a.x, a.y, a.z, a.w, b.x, b.y, b.z, b.w};
                half8 hi, lo;
#pragma unroll
                for (int j = 0; j < 8; ++j) {
                    float x = relu_f(v[j]);
                    _Float16 h16 = (_Float16)x;
                    hi[j] = h16;
                    lo[j] = (_Float16)(x - (float)h16);
                }
                *(half8*)(Hh + (size_t)idx * EMBED + lane * 8) = hi;
                *(half8*)(Hl + (size_t)idx * EMBED + lane * 8) = lo;
            }
        }
    }
}

// ---------------------------------------------------------------------------
// Big-level GEMM (h=1..4). Block 64 rows x 128 cols, 4 waves 2x2, BK=128
// (8 K-chunks), 96 KB LDS staged via global_load_lds w=16 in fragment order.
__global__ __launch_bounds__(256, 1)
void gemm_big(const _Float16* H,                // Hh; Hl = H + hoff
              const _Float16* __restrict__ Wp,  // Whp; Wlp = Wp + WOFF
              const float* __restrict__ bW,
              _Float16* Hh, _Float16* Hl,
              int h, int M, int hoff)
{
    __shared__ _Float16 lds[49152];             // A[0,16384) B[16384,49152)

    int tid = threadIdx.x;
    int wave = tid >> 6, lane = tid & 63;
    int q = lane >> 4, r = lane & 15;
    int wm = wave >> 1, wn = wave & 1;
    int bm0 = blockIdx.x * 64, bn0 = blockIdx.y * 128;

    int ms = bm0 + wave * 16 + r;
    if (ms >= M) ms = M - 1;
    int node_s = ((ms + 1) << (h + 1)) - 2 - __popc(ms);
    int aL = (node_s - (1 << h)) * EMBED + q * 8;
    int aR = (node_s - 1) * EMBED + q * 8;

    floatx4 acc[2][4];
#pragma unroll
    for (int i = 0; i < 2; ++i)
#pragma unroll
        for (int j = 0; j < 4; ++j) acc[i][j] = (floatx4){0.f, 0.f, 0.f, 0.f};

    for (int kc = 0; kc < 8; ++kc) {            // BK=128
        int abase = ((kc < 4) ? aL : aR) + (kc & 3) * 128;
#pragma unroll
        for (int i = 0; i < 8; ++i) {           // A: i = s2*2 + hl
            int s2 = i >> 1, hl = i & 1;
            const _Float16* gp = H + abase + s2 * 32 + (hl ? hoff : 0);
            GLDS16(gp, &lds[(wave * 8 + i) * 512]);
        }
#pragma unroll
        for (int j = 0; j < 16; ++j) {          // B slot id = wave*16 + j
            int u = wave * 2 + (j >> 3), s2 = (j >> 1) & 3, hl = j & 1;
            const _Float16* gp = Wp + (size_t)(blockIdx.y * 8 + u) * 16384
                               + (kc * 4 + s2) * 512 + (hl ? WOFF : 0) + lane * 8;
            GLDS16(gp, &lds[16384 + (wave * 16 + j) * 512]);
        }
        __syncthreads();

#pragma unroll
        for (int s2 = 0; s2 < 4; ++s2) {
            half8 ah[2], al[2], bh[4], bl[4];
#pragma unroll
            for (int t2 = 0; t2 < 2; ++t2) {
                int t = wm * 2 + t2;
                ah[t2] = *(const half8*)&lds[(t * 8 + s2 * 2 + 0) * 512 + lane * 8];
                al[t2] = *(const half8*)&lds[(t * 8 + s2 * 2 + 1) * 512 + lane * 8];
            }
#pragma unroll
            for (int u2 = 0; u2 < 4; ++u2) {
                int u = wn * 4 + u2;
                bh[u2] = *(const half8*)&lds[16384 + (u * 8 + s2 * 2 + 0) * 512 + lane * 8];
                bl[u2] = *(const half8*)&lds[16384 + (u * 8 + s2 * 2 + 1) * 512 + lane * 8];
            }
#pragma unroll
            for (int t2 = 0; t2 < 2; ++t2)
#pragma unroll
                for (int u2 = 0; u2 < 4; ++u2) {
                    acc[t2][u2] = __builtin_amdgcn_mfma_f32_16x16x32_f16(ah[t2], bh[u2], acc[t2][u2], 0, 0, 0);
                    acc[t2][u2] = __builtin_amdgcn_mfma_f32_16x16x32_f16(ah[t2], bl[u2], acc[t2][u2], 0, 0, 0);
                    acc[t2][u2] = __builtin_amdgcn_mfma_f32_16x16x32_f16(al[t2], bh[u2], acc[t2][u2], 0, 0, 0);
                }
        }
        __syncthreads();
    }

#pragma unroll
    for (int t2 = 0; t2 < 2; ++t2)
#pragma unroll
        for (int reg = 0; reg < 4; ++reg) {
            int m = bm0 + (wm * 2 + t2) * 16 + q * 4 + reg;
            if (m < M) {
                int node = ((m + 1) << (h + 1)) - 2 - __popc(m);
#pragma unroll
                for (int u2 = 0; u2 < 4; ++u2) {
                    int col = bn0 + (wn * 4 + u2) * 16 + r;
                    float v = relu_f(acc[t2][u2][reg] + bW[col]);
                    _Float16 hi = (_Float16)v;
                    Hh[(size_t)node * EMBED + col] = hi;
                    Hl[(size_t)node * EMBED + col] = (_Float16)(v - (float)hi);
                }
            }
        }
}

// ---------------------------------------------------------------------------
// Small-level split-K kernel (h=5..13). Block = one 16x16 output tile;
// 4 waves each own a K=256 slice (8 k-steps x 3-term MFMA), fp32 partials
// reduced via LDS, fused bias+relu+split epilogue. grid = (ceil(M/16), 32).
__global__ __launch_bounds__(256)
void gemm_splitk(const _Float16* __restrict__ Hh, const _Float16* __restrict__ Hl,
                 const _Float16* __restrict__ Wp,   // Whp; Wlp = Wp + WOFF
                 const float* __restrict__ bW,
                 _Float16* HhO, _Float16* HlO,
                 int h, int M)
{
    __shared__ float red[4 * 256];

    int tid = threadIdx.x;
    int wave = tid >> 6, lane = tid & 63;
    int q = lane >> 4, r = lane & 15;
    int mt = blockIdx.x, u = blockIdx.y;

    int m = mt * 16 + r;
    if (m >= M) m = M - 1;
    int idx = ((m + 1) << (h + 1)) - 2 - __popc(m);
    int childRow = (wave < 2) ? (idx - (1 << h)) : (idx - 1);
    int kbase = (wave & 1) * 256;                // offset within child row
    const _Float16* pAh = Hh + (size_t)childRow * EMBED + kbase + q * 8;
    const _Float16* pAl = Hl + (size_t)childRow * EMBED + kbase + q * 8;
    const _Float16* pB  = Wp + (size_t)u * 16384 + (size_t)(wave * 8) * 512 + lane * 8;

    floatx4 acc = (floatx4){0.f, 0.f, 0.f, 0.f};
#pragma unroll
    for (int s = 0; s < 8; ++s) {
        half8 ah = *(const half8*)(pAh + s * 32);
        half8 al = *(const half8*)(pAl + s * 32);
        half8 bh = *(const half8*)(pB + s * 512);
        half8 bl = *(const half8*)(pB + s * 512 + WOFF);
        acc = __builtin_amdgcn_mfma_f32_16x16x32_f16(ah, bh, acc, 0, 0, 0);
        acc = __builtin_amdgcn_mfma_f32_16x16x32_f16(ah, bl, acc, 0, 0, 0);
        acc = __builtin_amdgcn_mfma_f32_16x16x32_f16(al, bh, acc, 0, 0, 0);
    }
#pragma unroll
    for (int reg = 0; reg < 4; ++reg)
        red[wave * 256 + (q * 4 + reg) * 16 + r] = acc[reg];
    __syncthreads();

    int row = tid >> 4, col = tid & 15;
    float v = red[row * 16 + col] + red[256 + row * 16 + col]
            + red[512 + row * 16 + col] + red[768 + row * 16 + col];
    int mm = mt * 16 + row;
    if (mm < M) {
        int node = ((mm + 1) << (h + 1)) - 2 - __popc(mm);
        int colg = u * 16 + col;
        float x = relu_f(v + bW[colg]);
        _Float16 hi = (_Float16)x;
        HhO[(size_t)node * EMBED + colg] = hi;
        HlO[(size_t)node * EMBED + colg] = (_Float16)(x - (float)hi);
    }
}

// ---------------------------------------------------------------------------
__global__ __launch_bounds__(256)
void out_kernel(const _Float16* __restrict__ Hh, const _Float16* __restrict__ Hl,
                const float* __restrict__ P, const float* __restrict__ bP,
                float* __restrict__ out, int nNodes)
{
    int t = blockIdx.x * 256 + threadIdx.x;
    int node = t >> 6, lane = t & 63;
    if (node >= nNodes) return;
    half8 hv = *(const half8*)(Hh + (size_t)node * EMBED + lane * 8);
    half8 lv = *(const half8*)(Hl + (size_t)node * EMBED + lane * 8);
    float hx[8];
#pragma unroll
    for (int j = 0; j < 8; ++j) hx[j] = (float)hv[j] + (float)lv[j];
    float s[5];
#pragma unroll
    for (int c = 0; c < 5; ++c) {
        const float* p = P + c * EMBED + lane * 8;
        float4 p0 = *(const float4*)p;
        float4 p1 = *(const float4*)(p + 4);
        s[c] = hx[0] * p0.x + hx[1] * p0.y + hx[2] * p0.z + hx[3] * p0.w
             + hx[4] * p1.x + hx[5] * p1.y + hx[6] * p1.z + hx[7] * p1.w;
    }
#pragma unroll
    for (int o = 32; o > 0; o >>= 1)
#pragma unroll
        for (int c = 0; c < 5; ++c)
            s[c] += __shfl_down(s[c], o, 64);
    if (lane == 0) {
#pragma unroll
        for (int c = 0; c < 5; ++c)
            out[(size_t)node * 5 + c] = s[c] + bP[c];
    }
}

// ---------------------------------------------------------------------------
extern "C" void kernel_launch(void* const* d_in, const int* in_sizes, int n_in,
                              void* d_out, int out_size, void* d_ws, size_t ws_size,
                              hipStream_t stream)
{
    const int*   word = (const int*)d_in[1];
    const float* emb  = (const float*)d_in[4];
    const float* W    = (const float*)d_in[5];
    const float* bW   = (const float*)d_in[6];
    const float* P    = (const float*)d_in[7];
    const float* bP   = (const float*)d_in[8];
    float* out = (float*)d_out;

    int nNodes  = in_sizes[0];            // 16383
    int nLeaves = (nNodes + 1) / 2;       // 8192

    int hoff = (nNodes + 1) * EMBED;      // halves between Hh and Hl
    _Float16* Hh  = (_Float16*)d_ws;
    _Float16* Hl  = Hh + hoff;
    _Float16* Whp = Hl + hoff;            // hi; lo at +WOFF

    packleaf<<<dim3(256), dim3(256), 0, stream>>>(
        W, emb, word, Whp, Hh, Hl, nLeaves);
    for (int h = 1; h <= 4; ++h) {
        int M = 1 << (13 - h);
        gemm_big<<<dim3(M / 64, 4), dim3(256), 0, stream>>>(
            Hh, Whp, bW, Hh, Hl, h, M, hoff);
    }
    for (int h = 5; h <= 13; ++h) {
        int M = 1 << (13 - h);
        gemm_splitk<<<dim3((M + 15) / 16, 32), dim3(256), 0, stream>>>(
            Hh, Hl, Whp, bW, Hh, Hl, h, M);
    }
    out_kernel<<<dim3((nNodes * 64 + 255) / 256), dim3(256), 0, stream>>>(
        Hh, Hl, P, bP, out, nNodes);
}

// Round 9
// 252.761 us; speedup vs baseline: 3.2849x; 1.0816x over previous
//
#include <hip/hip_runtime.h>

// RecursiveNN, perfect binary tree, 8192 leaves, EMBED=512.
// idx(h,m) = ((m+1)<<(h+1)) - 2 - popc(m); left = idx - (1<<h); right = idx-1.
// fp16 hi+lo split H and W, 3-term MFMA (hh,hl,lh) => fp32-level accuracy.
// ALL sync via kernel boundaries (intra-kernel grid sync on MI355X: fence
// storms / RMW-spin serialization / replay crash — abandoned).
// Round-8 lesson: LDS-staged 64x128 blocks at <=1 block/CU have a ~44us
// constant serial path regardless of level size. All levels now use split-K
// micro-tile kernels (short per-block path, many blocks/CU):
//   h=1..4: 32x32 tile, 4-way K-split (64KB L2 per block)   [new]
//   h=5..13: 16x16 tile, 4-way K-split                      [proven]

#define EMBED 512
#define K2    1024
#define WOFF  (EMBED * K2)

typedef _Float16 half8 __attribute__((ext_vector_type(8)));
typedef _Float16 half4 __attribute__((ext_vector_type(4)));
typedef float    floatx4 __attribute__((ext_vector_type(4)));

__device__ __forceinline__ float relu_f(float x) { return fmaxf(x, 0.0f); }

// ---------------------------------------------------------------------------
// pack W into fp16 hi/lo MFMA-B fragment order + leaf embedding gather.
__global__ __launch_bounds__(256)
void packleaf(const float* __restrict__ W, const float* __restrict__ emb,
              const int* __restrict__ word,
              _Float16* __restrict__ Whp,       // lo at +WOFF
              _Float16* __restrict__ Hh, _Float16* __restrict__ Hl,
              int nLeaves)
{
    int tid = threadIdx.x;
    int wave = tid >> 6, lane = tid & 63;

    {   // ---- pack W: 65536 jobs = 256 blocks x 256 threads
        int t = blockIdx.x * 256 + tid;
        int n = t >> 7, kc = t & 127;
        const float* src = W + (size_t)n * K2 + kc * 8;
        int s = kc >> 2, quad = kc & 3;
        int ln = (quad << 4) | (n & 15);
        size_t off = (size_t)(n >> 4) * 16384 + (size_t)s * 512 + (size_t)ln * 8;
        half8 hi, lo;
#pragma unroll
        for (int j = 0; j < 8; ++j) {
            float w = src[j];
            _Float16 h16 = (_Float16)w;
            hi[j] = h16;
            lo[j] = (_Float16)(w - (float)h16);
        }
        *(half8*)(Whp + off) = hi;
        *(half8*)(Whp + WOFF + off) = lo;
    }
    {   // ---- leaves: 8192 = 256 blocks x 4 waves x 8
#pragma unroll
        for (int i = 0; i < 8; ++i) {
            int m = blockIdx.x * 32 + wave * 8 + i;
            if (m < nLeaves) {
                int idx = 2 * m - __popc(m);
                int wd = word[idx];
                const float4* src = (const float4*)(emb + (size_t)wd * EMBED) + lane * 2;
                float4 a = src[0], b = src[1];
                float v[8] = {a.x, a.y, a.z, a.w, b.x, b.y, b.z, b.w};
                half8 hi, lo;
#pragma unroll
                for (int j = 0; j < 8; ++j) {
                    float x = relu_f(v[j]);
                    _Float16 h16 = (_Float16)x;
                    hi[j] = h16;
                    lo[j] = (_Float16)(x - (float)h16);
                }
                *(half8*)(Hh + (size_t)idx * EMBED + lane * 8) = hi;
                *(half8*)(Hl + (size_t)idx * EMBED + lane * 8) = lo;
            }
        }
    }
}

// ---------------------------------------------------------------------------
// Big-level split-K kernel (h=1..4, M multiple of 32). Block = 32x32 output
// tile; 4 waves each own a K=256 slice (8 k-steps, 2x2 16x16 MFMA tiles,
// 3-term). fp32 partials via 16KB LDS, fused bias+relu+hi/lo epilogue.
// grid = (M/32, 16). Per-block L2 traffic 64KB; ~8 blocks/CU at h=1.
__global__ __launch_bounds__(256)
void gemm_splitk32(const _Float16* __restrict__ Hh, const _Float16* __restrict__ Hl,
                   const _Float16* __restrict__ Wp,   // Whp; Wlp = Wp + WOFF
                   const float* __restrict__ bW,
                   _Float16* HhO, _Float16* HlO,
                   int h, int M)
{
    __shared__ float red[4096];                 // 4 K-slices x 32x32 fp32

    int tid = threadIdx.x;
    int wave = tid >> 6, lane = tid & 63;
    int q = lane >> 4, r = lane & 15;
    int m0 = blockIdx.x * 32, n0 = blockIdx.y * 32;

    // A-fragment pointers for the two 16-row tiles (lane r = row within tile)
    const _Float16 *pAh[2], *pAl[2];
#pragma unroll
    for (int mi = 0; mi < 2; ++mi) {
        int m = m0 + mi * 16 + r;
        int idx = ((m + 1) << (h + 1)) - 2 - __popc(m);
        int childRow = (wave < 2) ? (idx - (1 << h)) : (idx - 1);
        int kbase = (wave & 1) * 256;           // K-slice offset within child
        pAh[mi] = Hh + (size_t)childRow * EMBED + kbase + q * 8;
        pAl[mi] = Hl + (size_t)childRow * EMBED + kbase + q * 8;
    }
    // B-fragment pointers for the two 16-col tiles
    const _Float16* pB[2];
#pragma unroll
    for (int ui = 0; ui < 2; ++ui)
        pB[ui] = Wp + (size_t)(blockIdx.y * 2 + ui) * 16384
               + (size_t)(wave * 8) * 512 + lane * 8;

    floatx4 acc[2][2];
#pragma unroll
    for (int mi = 0; mi < 2; ++mi)
#pragma unroll
        for (int ui = 0; ui < 2; ++ui) acc[mi][ui] = (floatx4){0.f, 0.f, 0.f, 0.f};

#pragma unroll
    for (int s = 0; s < 8; ++s) {
        half8 ah[2], al[2], bh[2], bl[2];
#pragma unroll
        for (int mi = 0; mi < 2; ++mi) {
            ah[mi] = *(const half8*)(pAh[mi] + s * 32);
            al[mi] = *(const half8*)(pAl[mi] + s * 32);
        }
#pragma unroll
        for (int ui = 0; ui < 2; ++ui) {
            bh[ui] = *(const half8*)(pB[ui] + s * 512);
            bl[ui] = *(const half8*)(pB[ui] + s * 512 + WOFF);
        }
#pragma unroll
        for (int mi = 0; mi < 2; ++mi)
#pragma unroll
            for (int ui = 0; ui < 2; ++ui) {
                acc[mi][ui] = __builtin_amdgcn_mfma_f32_16x16x32_f16(ah[mi], bh[ui], acc[mi][ui], 0, 0, 0);
                acc[mi][ui] = __builtin_amdgcn_mfma_f32_16x16x32_f16(ah[mi], bl[ui], acc[mi][ui], 0, 0, 0);
                acc[mi][ui] = __builtin_amdgcn_mfma_f32_16x16x32_f16(al[mi], bh[ui], acc[mi][ui], 0, 0, 0);
            }
    }

    // partials: C/D layout row = q*4+reg, col = r (per 16x16 tile)
#pragma unroll
    for (int mi = 0; mi < 2; ++mi)
#pragma unroll
        for (int ui = 0; ui < 2; ++ui)
#pragma unroll
            for (int reg = 0; reg < 4; ++reg)
                red[wave * 1024 + (mi * 16 + q * 4 + reg) * 32 + ui * 16 + r]
                    = acc[mi][ui][reg];
    __syncthreads();

    // combine: thread -> (row, 4 consecutive cols); sum 4 slices, epilogue.
    int row = tid >> 3, c4 = (tid & 7) * 4;
    int mm = m0 + row;
    int node = ((mm + 1) << (h + 1)) - 2 - __popc(mm);
    half4 hi4, lo4;
#pragma unroll
    for (int j = 0; j < 4; ++j) {
        int c = row * 32 + c4 + j;
        float v = red[c] + red[1024 + c] + red[2048 + c] + red[3072 + c];
        float x = relu_f(v + bW[n0 + c4 + j]);
        _Float16 hi = (_Float16)x;
        hi4[j] = hi;
        lo4[j] = (_Float16)(x - (float)hi);
    }
    *(half4*)(HhO + (size_t)node * EMBED + n0 + c4) = hi4;
    *(half4*)(HlO + (size_t)node * EMBED + n0 + c4) = lo4;
}

// ---------------------------------------------------------------------------
// Small-level split-K kernel (h=5..13). Block = one 16x16 output tile;
// 4 waves each own a K=256 slice, fp32 partials via LDS, fused epilogue.
// grid = (ceil(M/16), 32).
__global__ __launch_bounds__(256)
void gemm_splitk(const _Float16* __restrict__ Hh, const _Float16* __restrict__ Hl,
                 const _Float16* __restrict__ Wp,   // Whp; Wlp = Wp + WOFF
                 const float* __restrict__ bW,
                 _Float16* HhO, _Float16* HlO,
                 int h, int M)
{
    __shared__ float red[4 * 256];

    int tid = threadIdx.x;
    int wave = tid >> 6, lane = tid & 63;
    int q = lane >> 4, r = lane & 15;
    int mt = blockIdx.x, u = blockIdx.y;

    int m = mt * 16 + r;
    if (m >= M) m = M - 1;
    int idx = ((m + 1) << (h + 1)) - 2 - __popc(m);
    int childRow = (wave < 2) ? (idx - (1 << h)) : (idx - 1);
    int kbase = (wave & 1) * 256;                // offset within child row
    const _Float16* pAh = Hh + (size_t)childRow * EMBED + kbase + q * 8;
    const _Float16* pAl = Hl + (size_t)childRow * EMBED + kbase + q * 8;
    const _Float16* pB  = Wp + (size_t)u * 16384 + (size_t)(wave * 8) * 512 + lane * 8;

    floatx4 acc = (floatx4){0.f, 0.f, 0.f, 0.f};
#pragma unroll
    for (int s = 0; s < 8; ++s) {
        half8 ah = *(const half8*)(pAh + s * 32);
        half8 al = *(const half8*)(pAl + s * 32);
        half8 bh = *(const half8*)(pB + s * 512);
        half8 bl = *(const half8*)(pB + s * 512 + WOFF);
        acc = __builtin_amdgcn_mfma_f32_16x16x32_f16(ah, bh, acc, 0, 0, 0);
        acc = __builtin_amdgcn_mfma_f32_16x16x32_f16(ah, bl, acc, 0, 0, 0);
        acc = __builtin_amdgcn_mfma_f32_16x16x32_f16(al, bh, acc, 0, 0, 0);
    }
#pragma unroll
    for (int reg = 0; reg < 4; ++reg)
        red[wave * 256 + (q * 4 + reg) * 16 + r] = acc[reg];
    __syncthreads();

    int row = tid >> 4, col = tid & 15;
    float v = red[row * 16 + col] + red[256 + row * 16 + col]
            + red[512 + row * 16 + col] + red[768 + row * 16 + col];
    int mm = mt * 16 + row;
    if (mm < M) {
        int node = ((mm + 1) << (h + 1)) - 2 - __popc(mm);
        int colg = u * 16 + col;
        float x = relu_f(v + bW[colg]);
        _Float16 hi = (_Float16)x;
        HhO[(size_t)node * EMBED + colg] = hi;
        HlO[(size_t)node * EMBED + colg] = (_Float16)(x - (float)hi);
    }
}

// ---------------------------------------------------------------------------
__global__ __launch_bounds__(256)
void out_kernel(const _Float16* __restrict__ Hh, const _Float16* __restrict__ Hl,
                const float* __restrict__ P, const float* __restrict__ bP,
                float* __restrict__ out, int nNodes)
{
    int t = blockIdx.x * 256 + threadIdx.x;
    int node = t >> 6, lane = t & 63;
    if (node >= nNodes) return;
    half8 hv = *(const half8*)(Hh + (size_t)node * EMBED + lane * 8);
    half8 lv = *(const half8*)(Hl + (size_t)node * EMBED + lane * 8);
    float hx[8];
#pragma unroll
    for (int j = 0; j < 8; ++j) hx[j] = (float)hv[j] + (float)lv[j];
    float s[5];
#pragma unroll
    for (int c = 0; c < 5; ++c) {
        const float* p = P + c * EMBED + lane * 8;
        float4 p0 = *(const float4*)p;
        float4 p1 = *(const float4*)(p + 4);
        s[c] = hx[0] * p0.x + hx[1] * p0.y + hx[2] * p0.z + hx[3] * p0.w
             + hx[4] * p1.x + hx[5] * p1.y + hx[6] * p1.z + hx[7] * p1.w;
    }
#pragma unroll
    for (int o = 32; o > 0; o >>= 1)
#pragma unroll
        for (int c = 0; c < 5; ++c)
            s[c] += __shfl_down(s[c], o, 64);
    if (lane == 0) {
#pragma unroll
        for (int c = 0; c < 5; ++c)
            out[(size_t)node * 5 + c] = s[c] + bP[c];
    }
}

// ---------------------------------------------------------------------------
extern "C" void kernel_launch(void* const* d_in, const int* in_sizes, int n_in,
                              void* d_out, int out_size, void* d_ws, size_t ws_size,
                              hipStream_t stream)
{
    const int*   word = (const int*)d_in[1];
    const float* emb  = (const float*)d_in[4];
    const float* W    = (const float*)d_in[5];
    const float* bW   = (const float*)d_in[6];
    const float* P    = (const float*)d_in[7];
    const float* bP   = (const float*)d_in[8];
    float* out = (float*)d_out;

    int nNodes  = in_sizes[0];            // 16383
    int nLeaves = (nNodes + 1) / 2;       // 8192

    int hoff = (nNodes + 1) * EMBED;      // halves between Hh and Hl
    _Float16* Hh  = (_Float16*)d_ws;
    _Float16* Hl  = Hh + hoff;
    _Float16* Whp = Hl + hoff;            // hi; lo at +WOFF

    packleaf<<<dim3(256), dim3(256), 0, stream>>>(
        W, emb, word, Whp, Hh, Hl, nLeaves);
    for (int h = 1; h <= 4; ++h) {        // M = 4096,2048,1024,512
        int M = 1 << (13 - h);
        gemm_splitk32<<<dim3(M / 32, 16), dim3(256), 0, stream>>>(
            Hh, Hl, Whp, bW, Hh, Hl, h, M);
    }
    for (int h = 5; h <= 13; ++h) {       // M = 256..1
        int M = 1 << (13 - h);
        gemm_splitk<<<dim3((M + 15) / 16, 32), dim3(256), 0, stream>>>(
            Hh, Hl, Whp, bW, Hh, Hl, h, M);
    }
    out_kernel<<<dim3((nNodes * 64 + 255) / 256), dim3(256), 0, stream>>>(
        Hh, Hl, P, bP, out, nNodes);
}

// Round 10
// 236.241 us; speedup vs baseline: 3.5146x; 1.0699x over previous
//
#include <hip/hip_runtime.h>

// RecursiveNN, perfect binary tree, 8192 leaves, EMBED=512.
// LEVEL-MAJOR H layout: level h stored as dense [M_h][512] at row offset
// roff(h) = 16384 - 2^(14-h). Children of (h,m) are (h-1,2m),(h-1,2m+1), so
// level h's GEMM input [M][1024] is EXACTLY the previous level's buffer —
// no gather, no tree indexing in hot loops. Post-order node id (for the final
// scatter only): idx(h,m) = ((m+1)<<(h+1)) - 2 - popc(m).
// Numerics: fp16 hi+lo split H and W, 3-term MFMA (hh,hl,lh) => fp32-level.
// All sync via kernel boundaries (intra-kernel grid sync abandoned: fence
// storms / RMW-spin serialization / replay crash).
// L2 lesson (r2/r9 + m97): 16B/lane streams cap at ~12-13 TB/s -> the lever is
// TRAFFIC, i.e. tile size. h=1,2: 64x64 staged tiles (512KB/block). h=3,4:
// 32x32 split-K. h>=5: 16x16 split-K.

#define EMBED 512
#define K2    1024
#define WOFF  (EMBED * K2)

typedef _Float16 half8 __attribute__((ext_vector_type(8)));
typedef float    floatx4 __attribute__((ext_vector_type(4)));

__device__ __forceinline__ float relu_f(float x) { return fmaxf(x, 0.0f); }

#define GLDS16(gp, lp)                                                        \
    __builtin_amdgcn_global_load_lds(                                         \
        (const __attribute__((address_space(1))) void*)(gp),                  \
        (__attribute__((address_space(3))) void*)(lp), 16, 0, 0)

#define MFMA16(a, b, c) __builtin_amdgcn_mfma_f32_16x16x32_f16(a, b, c, 0, 0, 0)

// ---------------------------------------------------------------------------
// pack W into fp16 hi/lo MFMA-B fragment order + leaves into level-0 rows.
__global__ __launch_bounds__(256)
void packleaf(const float* __restrict__ W, const float* __restrict__ emb,
              const int* __restrict__ word,
              _Float16* __restrict__ Whp,       // lo at +WOFF
              _Float16* __restrict__ Hh, _Float16* __restrict__ Hl,
              int nLeaves)
{
    int tid = threadIdx.x;
    int wave = tid >> 6, lane = tid & 63;

    {   // ---- pack W: 65536 jobs = 256 blocks x 256 threads
        int t = blockIdx.x * 256 + tid;
        int n = t >> 7, kc = t & 127;
        const float* src = W + (size_t)n * K2 + kc * 8;
        int s = kc >> 2, quad = kc & 3;
        int ln = (quad << 4) | (n & 15);
        size_t off = (size_t)(n >> 4) * 16384 + (size_t)s * 512 + (size_t)ln * 8;
        half8 hi, lo;
#pragma unroll
        for (int j = 0; j < 8; ++j) {
            float w = src[j];
            _Float16 h16 = (_Float16)w;
            hi[j] = h16;
            lo[j] = (_Float16)(w - (float)h16);
        }
        *(half8*)(Whp + off) = hi;
        *(half8*)(Whp + WOFF + off) = lo;
    }
    {   // ---- leaves -> level-0 rows (m-order, coalesced)
#pragma unroll
        for (int i = 0; i < 8; ++i) {
            int m = blockIdx.x * 32 + wave * 8 + i;
            if (m < nLeaves) {
                int wd = word[2 * m - __popc(m)];    // post-order leaf id
                const float4* src = (const float4*)(emb + (size_t)wd * EMBED) + lane * 2;
                float4 a = src[0], b = src[1];
                float v[8] = {a.x, a.y, a.z, a.w, b.x, b.y, b.z, b.w};
                half8 hi, lo;
#pragma unroll
                for (int j = 0; j < 8; ++j) {
                    float x = relu_f(v[j]);
                    _Float16 h16 = (_Float16)x;
                    hi[j] = h16;
                    lo[j] = (_Float16)(x - (float)h16);
                }
                *(half8*)(Hh + (size_t)m * EMBED + lane * 8) = hi;
                *(half8*)(Hl + (size_t)m * EMBED + lane * 8) = lo;
            }
        }
    }
}

// ---------------------------------------------------------------------------
// Level GEMM for h=1,2 (M multiple of 64). Block = 64 rows x 64 cols,
// 4 waves: slice = wave>>1 (K-half = child), nh = wave&1 (col-half).
// Per BK=64 chunk: A staged via global_load_lds (per-lane row gather on the
// global side) into fragment-order LDS slots -> conflict-free ds reads.
// B direct from packed-fragment global (contiguous, L2-resident).
// Cross-slice fp32 reduce via LDS, fused bias+relu+hi/lo epilogue.
__global__ __launch_bounds__(256)
void gemm_lvl(const _Float16* __restrict__ Ap,  // prev level base hi (lo at +hoff)
              const _Float16* __restrict__ Wp,  // Whp (lo at +WOFF)
              const float* __restrict__ bW,
              _Float16* __restrict__ Cp,        // cur level base hi (lo at +hoff)
              int hoff)
{
    __shared__ _Float16 As[16384];              // 32 KB: 32 fragment slots x 1 KB
    __shared__ float Red[4096];                 // 16 KB: 64x64 fp32

    int tid = threadIdx.x;
    int wave = tid >> 6, lane = tid & 63;
    int q = lane >> 4, r = lane & 15;
    int slice = wave >> 1, nh = wave & 1;
    int bm0 = blockIdx.x * 64, bn0 = blockIdx.y * 64;

    // Staging source (wave stages slots (slice, t, s2, hl=nh)):
    // A[m][1024] view == prev buffer + m*1024 halves.
    const _Float16* Asrc = Ap + (size_t)(nh ? hoff : 0)
                         + (size_t)(bm0 + r) * 1024 + slice * 512 + q * 8;

    floatx4 acc[4][2];
#pragma unroll
    for (int t = 0; t < 4; ++t)
#pragma unroll
        for (int u = 0; u < 2; ++u) acc[t][u] = (floatx4){0.f, 0.f, 0.f, 0.f};

    for (int kc = 0; kc < 8; ++kc) {
        // ---- stage 8 slots (1 KB each): slot = slice*16 + t*4 + s2*2 + nh
#pragma unroll
        for (int t = 0; t < 4; ++t)
#pragma unroll
            for (int s2 = 0; s2 < 2; ++s2) {
                const _Float16* gp = Asrc + t * (16 * 1024) + kc * 64 + s2 * 32;
                GLDS16(gp, &As[(slice * 16 + t * 4 + s2 * 2 + nh) * 512]);
            }
        __syncthreads();

#pragma unroll
        for (int s2 = 0; s2 < 2; ++s2) {
            half8 bh[2], bl[2];
#pragma unroll
            for (int u = 0; u < 2; ++u) {
                const _Float16* pb = Wp + (size_t)(blockIdx.y * 4 + nh * 2 + u) * 16384
                                   + (size_t)(slice * 16 + kc * 2 + s2) * 512 + lane * 8;
                bh[u] = *(const half8*)pb;
                bl[u] = *(const half8*)(pb + WOFF);
            }
#pragma unroll
            for (int t = 0; t < 4; ++t) {
                half8 ah = *(const half8*)&As[(slice * 16 + t * 4 + s2 * 2 + 0) * 512 + lane * 8];
                half8 al = *(const half8*)&As[(slice * 16 + t * 4 + s2 * 2 + 1) * 512 + lane * 8];
#pragma unroll
                for (int u = 0; u < 2; ++u) {
                    acc[t][u] = MFMA16(ah, bh[u], acc[t][u]);
                    acc[t][u] = MFMA16(ah, bl[u], acc[t][u]);
                    acc[t][u] = MFMA16(al, bh[u], acc[t][u]);
                }
            }
        }
        __syncthreads();
    }

    // ---- cross-slice reduce + epilogue (C/D: row = q*4+reg, col = r)
    if (slice == 1) {
#pragma unroll
        for (int t = 0; t < 4; ++t)
#pragma unroll
            for (int u = 0; u < 2; ++u)
#pragma unroll
                for (int reg = 0; reg < 4; ++reg)
                    Red[(t * 16 + q * 4 + reg) * 64 + nh * 32 + u * 16 + r]
                        = acc[t][u][reg];
    }
    __syncthreads();
    if (slice == 0) {
#pragma unroll
        for (int t = 0; t < 4; ++t)
#pragma unroll
            for (int u = 0; u < 2; ++u) {
                int col = bn0 + nh * 32 + u * 16 + r;
                float bw = bW[col];
#pragma unroll
                for (int reg = 0; reg < 4; ++reg) {
                    int ml = t * 16 + q * 4 + reg;
                    float v = acc[t][u][reg]
                            + Red[ml * 64 + nh * 32 + u * 16 + r];
                    float x = relu_f(v + bw);
                    _Float16 hi = (_Float16)x;
                    size_t o = (size_t)(bm0 + ml) * EMBED + col;
                    Cp[o] = hi;
                    Cp[o + hoff] = (_Float16)(x - (float)hi);
                }
            }
    }
}

// ---------------------------------------------------------------------------
// 32x32 split-K kernel (h=3,4; M multiple of 32). grid = (M/32, 16).
__global__ __launch_bounds__(256)
void gemm_splitk32(const _Float16* __restrict__ Ap, const _Float16* __restrict__ Wp,
                   const float* __restrict__ bW,
                   _Float16* __restrict__ Cp, int hoff)
{
    __shared__ float red[4096];

    int tid = threadIdx.x;
    int wave = tid >> 6, lane = tid & 63;
    int q = lane >> 4, r = lane & 15;
    int m0 = blockIdx.x * 32, n0 = blockIdx.y * 32;

    const _Float16 *pAh[2], *pAl[2];
#pragma unroll
    for (int mi = 0; mi < 2; ++mi) {
        int m = m0 + mi * 16 + r;
        int prow = 2 * m + (wave >> 1);          // child row in prev level
        int kb = (wave & 1) * 256;               // k-offset within child
        pAh[mi] = Ap + (size_t)prow * EMBED + kb + q * 8;
        pAl[mi] = pAh[mi] + hoff;
    }
    const _Float16* pB[2];
#pragma unroll
    for (int u = 0; u < 2; ++u)
        pB[u] = Wp + (size_t)(blockIdx.y * 2 + u) * 16384
              + (size_t)(wave * 8) * 512 + lane * 8;

    floatx4 acc[2][2];
#pragma unroll
    for (int mi = 0; mi < 2; ++mi)
#pragma unroll
        for (int u = 0; u < 2; ++u) acc[mi][u] = (floatx4){0.f, 0.f, 0.f, 0.f};

#pragma unroll
    for (int s = 0; s < 8; ++s) {
        half8 ah[2], al[2], bh[2], bl[2];
#pragma unroll
        for (int mi = 0; mi < 2; ++mi) {
            ah[mi] = *(const half8*)(pAh[mi] + s * 32);
            al[mi] = *(const half8*)(pAl[mi] + s * 32);
        }
#pragma unroll
        for (int u = 0; u < 2; ++u) {
            bh[u] = *(const half8*)(pB[u] + s * 512);
            bl[u] = *(const half8*)(pB[u] + s * 512 + WOFF);
        }
#pragma unroll
        for (int mi = 0; mi < 2; ++mi)
#pragma unroll
            for (int u = 0; u < 2; ++u) {
                acc[mi][u] = MFMA16(ah[mi], bh[u], acc[mi][u]);
                acc[mi][u] = MFMA16(ah[mi], bl[u], acc[mi][u]);
                acc[mi][u] = MFMA16(al[mi], bh[u], acc[mi][u]);
            }
    }

#pragma unroll
    for (int mi = 0; mi < 2; ++mi)
#pragma unroll
        for (int u = 0; u < 2; ++u)
#pragma unroll
            for (int reg = 0; reg < 4; ++reg)
                red[wave * 1024 + (mi * 16 + q * 4 + reg) * 32 + u * 16 + r]
                    = acc[mi][u][reg];
    __syncthreads();

    int row = tid >> 3, c4 = (tid & 7) * 4;
    _Float16 hi4[4], lo4[4];
#pragma unroll
    for (int j = 0; j < 4; ++j) {
        int c = row * 32 + c4 + j;
        float v = red[c] + red[1024 + c] + red[2048 + c] + red[3072 + c];
        float x = relu_f(v + bW[n0 + c4 + j]);
        _Float16 hi = (_Float16)x;
        hi4[j] = hi;
        lo4[j] = (_Float16)(x - (float)hi);
    }
    size_t o = (size_t)(m0 + row) * EMBED + n0 + c4;
#pragma unroll
    for (int j = 0; j < 4; ++j) { Cp[o + j] = hi4[j]; Cp[o + hoff + j] = lo4[j]; }
}

// ---------------------------------------------------------------------------
// 16x16 split-K kernel (h=5..13). grid = (ceil(M/16), 32).
__global__ __launch_bounds__(256)
void gemm_splitk(const _Float16* __restrict__ Ap, const _Float16* __restrict__ Wp,
                 const float* __restrict__ bW,
                 _Float16* __restrict__ Cp, int hoff, int M)
{
    __shared__ float red[1024];

    int tid = threadIdx.x;
    int wave = tid >> 6, lane = tid & 63;
    int q = lane >> 4, r = lane & 15;
    int mt = blockIdx.x, u = blockIdx.y;

    int m = mt * 16 + r;
    if (m >= M) m = M - 1;
    int prow = 2 * m + (wave >> 1);
    int kb = (wave & 1) * 256;
    const _Float16* pAh = Ap + (size_t)prow * EMBED + kb + q * 8;
    const _Float16* pAl = pAh + hoff;
    const _Float16* pB  = Wp + (size_t)u * 16384 + (size_t)(wave * 8) * 512 + lane * 8;

    floatx4 acc = (floatx4){0.f, 0.f, 0.f, 0.f};
#pragma unroll
    for (int s = 0; s < 8; ++s) {
        half8 ah = *(const half8*)(pAh + s * 32);
        half8 al = *(const half8*)(pAl + s * 32);
        half8 bh = *(const half8*)(pB + s * 512);
        half8 bl = *(const half8*)(pB + s * 512 + WOFF);
        acc = MFMA16(ah, bh, acc);
        acc = MFMA16(ah, bl, acc);
        acc = MFMA16(al, bh, acc);
    }
#pragma unroll
    for (int reg = 0; reg < 4; ++reg)
        red[wave * 256 + (q * 4 + reg) * 16 + r] = acc[reg];
    __syncthreads();

    int row = tid >> 4, col = tid & 15;
    float v = red[row * 16 + col] + red[256 + row * 16 + col]
            + red[512 + row * 16 + col] + red[768 + row * 16 + col];
    int mm = mt * 16 + row;
    if (mm < M) {
        int colg = u * 16 + col;
        float x = relu_f(v + bW[colg]);
        _Float16 hi = (_Float16)x;
        size_t o = (size_t)mm * EMBED + colg;
        Cp[o] = hi;
        Cp[o + hoff] = (_Float16)(x - (float)hi);
    }
}

// ---------------------------------------------------------------------------
// Projection: buffer row j (level-major) -> out[idx(h,m)]. Level decode:
// h = 13 - floor(log2(16383 - j)), m = j - (16384 - 2^(14-h)).
__global__ __launch_bounds__(256)
void out_kernel(const _Float16* __restrict__ Hh, const _Float16* __restrict__ Hl,
                const float* __restrict__ P, const float* __restrict__ bP,
                float* __restrict__ out, int nNodes)
{
    int t = blockIdx.x * 256 + threadIdx.x;
    int j = t >> 6, lane = t & 63;
    if (j >= nNodes) return;
    int v = nNodes - j;                         // 16383 - j >= 1
    int h = 13 - (31 - __clz(v));
    int m = j - ((nNodes + 1) - (1 << (13 - h + 1)));
    int node = ((m + 1) << (h + 1)) - 2 - __popc(m);

    half8 hv = *(const half8*)(Hh + (size_t)j * EMBED + lane * 8);
    half8 lv = *(const half8*)(Hl + (size_t)j * EMBED + lane * 8);
    float hx[8];
#pragma unroll
    for (int k = 0; k < 8; ++k) hx[k] = (float)hv[k] + (float)lv[k];
    float s[5];
#pragma unroll
    for (int c = 0; c < 5; ++c) {
        const float* p = P + c * EMBED + lane * 8;
        float4 p0 = *(const float4*)p;
        float4 p1 = *(const float4*)(p + 4);
        s[c] = hx[0] * p0.x + hx[1] * p0.y + hx[2] * p0.z + hx[3] * p0.w
             + hx[4] * p1.x + hx[5] * p1.y + hx[6] * p1.z + hx[7] * p1.w;
    }
#pragma unroll
    for (int o = 32; o > 0; o >>= 1)
#pragma unroll
        for (int c = 0; c < 5; ++c)
            s[c] += __shfl_down(s[c], o, 64);
    if (lane == 0) {
#pragma unroll
        for (int c = 0; c < 5; ++c)
            out[(size_t)node * 5 + c] = s[c] + bP[c];
    }
}

// ---------------------------------------------------------------------------
extern "C" void kernel_launch(void* const* d_in, const int* in_sizes, int n_in,
                              void* d_out, int out_size, void* d_ws, size_t ws_size,
                              hipStream_t stream)
{
    const int*   word = (const int*)d_in[1];
    const float* emb  = (const float*)d_in[4];
    const float* W    = (const float*)d_in[5];
    const float* bW   = (const float*)d_in[6];
    const float* P    = (const float*)d_in[7];
    const float* bP   = (const float*)d_in[8];
    float* out = (float*)d_out;

    int nNodes  = in_sizes[0];            // 16383
    int nLeaves = (nNodes + 1) / 2;       // 8192
    int nRows   = nNodes + 1;             // 16384

    int hoff = nRows * EMBED;             // halves between Hh and Hl
    _Float16* Hh  = (_Float16*)d_ws;
    _Float16* Hl  = Hh + hoff;
    _Float16* Whp = Hl + hoff;            // hi; lo at +WOFF

    // level row offsets: roff(h) = 16384 - 2^(14-h)
    auto roff = [&](int h) { return nRows - (1 << (14 - h)); };

    packleaf<<<dim3(256), dim3(256), 0, stream>>>(
        W, emb, word, Whp, Hh, Hl, nLeaves);

    for (int h = 1; h <= 2; ++h) {        // M = 4096, 2048
        int M = 1 << (13 - h);
        gemm_lvl<<<dim3(M / 64, 8), dim3(256), 0, stream>>>(
            Hh + (size_t)roff(h - 1) * EMBED, Whp, bW,
            Hh + (size_t)roff(h) * EMBED, hoff);
    }
    for (int h = 3; h <= 4; ++h) {        // M = 1024, 512
        int M = 1 << (13 - h);
        gemm_splitk32<<<dim3(M / 32, 16), dim3(256), 0, stream>>>(
            Hh + (size_t)roff(h - 1) * EMBED, Whp, bW,
            Hh + (size_t)roff(h) * EMBED, hoff);
    }
    for (int h = 5; h <= 13; ++h) {       // M = 256..1
        int M = 1 << (13 - h);
        gemm_splitk<<<dim3((M + 15) / 16, 32), dim3(256), 0, stream>>>(
            Hh + (size_t)roff(h - 1) * EMBED, Whp, bW,
            Hh + (size_t)roff(h) * EMBED, hoff, M);
    }
    out_kernel<<<dim3((nNodes * 64 + 255) / 256), dim3(256), 0, stream>>>(
        Hh, Hl, P, bP, out, nNodes);
}